// Round 17
// baseline (554.375 us; speedup 1.0000x reference)
//
#include <hip/hip_runtime.h>

#define NN 100000
#define DD 512
#define HH 256
#define KNB 5

typedef __attribute__((ext_vector_type(8))) short short8v;
typedef __attribute__((ext_vector_type(4))) short short4v;
typedef __attribute__((ext_vector_type(4))) float float4v;

static __device__ __forceinline__ float bf2f(unsigned short u) {
  union { unsigned int i; float f; } c;
  c.i = ((unsigned int)u) << 16;
  return c.f;
}
static __device__ __forceinline__ unsigned short f2bf(float f) {
  union { float f; unsigned int i; } c;
  c.f = f;
  unsigned int u = c.i;
  u += 0x7FFFu + ((u >> 16) & 1u);   // round-to-nearest-even
  return (unsigned short)(u >> 16);
}

// async global->LDS, 16B per lane; lds dest base must be wave-uniform
#define GLOAD16(g, l) __builtin_amdgcn_global_load_lds( \
    (const __attribute__((address_space(1))) unsigned int*)(g), \
    (__attribute__((address_space(3))) unsigned int*)(l), 16, 0, 0)

// bf16 conversion of the two input-projection weights
__global__ void cvt2(const float* __restrict__ s0, short* __restrict__ d0,
                     const float* __restrict__ s1, short* __restrict__ d1) {
  const int S1 = (HH * DD) / 4;
  int i = blockIdx.x * blockDim.x + threadIdx.x;
  if (i >= 2 * S1) return;
  const float* s = (i < S1) ? s0 : s1;
  short* d = (i < S1) ? d0 : d1;
  int j = (i < S1) ? i : i - S1;
  float4 v = reinterpret_cast<const float4*>(s)[j];
  short4v o;
  o[0] = (short)f2bf(v.x); o[1] = (short)f2bf(v.y);
  o[2] = (short)f2bf(v.z); o[3] = (short)f2bf(v.w);
  reinterpret_cast<short4v*>(d)[j] = o;
}

// Bcat [256][768] = [w0 | W01=w1@w0 | w2] bf16; bc[i] = b0+b1+b2 + w1@b0 (fp32)
__global__ void prep_w01(const float* __restrict__ w0, const float* __restrict__ w1,
                         const float* __restrict__ w2, const float* __restrict__ b0,
                         const float* __restrict__ b1, const float* __restrict__ b2,
                         short* __restrict__ Bcat, float* __restrict__ bc) {
  int i = blockIdx.x;      // output row 0..255
  int j = threadIdx.x;     // col 0..255
  Bcat[(size_t)i * 768 + j]       = (short)f2bf(w0[i * 256 + j]);
  Bcat[(size_t)i * 768 + 512 + j] = (short)f2bf(w2[i * 256 + j]);
  float acc = 0.f;
  for (int k = 0; k < 256; ++k)
    acc = fmaf(w1[i * 256 + k], w0[k * 256 + j], acc);
  Bcat[(size_t)i * 768 + 256 + j] = (short)f2bf(acc);
  if (j == 0) {
    float s = b0[i] + b1[i] + b2[i];
    for (int k = 0; k < 256; ++k) s = fmaf(w1[i * 256 + k], b0[k], s);
    bc[i] = s;
  }
}

// Projection (round-12 proven, 165 us best-of-6-schedules): all-reg-staged
// dbuf pipeline. BM=64, BN=256, BK=64, 8 waves (2M x 4N -> wave tile 32x64).
// LDS: B dbuf 64K + A dbuf 16K = 80 KB. (512,2): VGPR 64, no spill. FROZEN.
__global__ __launch_bounds__(512, 2) void proj_k(
    const float* __restrict__ Af0, const float* __restrict__ Af1,
    const short* __restrict__ Bw0, const short* __restrict__ Bw1,
    const float* __restrict__ bi0, const float* __restrict__ bi1,
    short* __restrict__ Cb0, short* __restrict__ Cb1)
{
  const float* Af = blockIdx.y ? Af1 : Af0;
  const short* Bw = blockIdx.y ? Bw1 : Bw0;
  const float* bias = blockIdx.y ? bi1 : bi0;
  short* Cb = blockIdx.y ? Cb1 : Cb0;

  __shared__ __align__(16) char BsRaw[2 * 256 * 64 * 2];  // 64 KB dbuf, XOR-swizzled
  __shared__ __align__(16) char AsRaw[2 * 64 * 64 * 2];   // 16 KB dbuf bf16

  const int tid = threadIdx.x;
  const int lane = tid & 63;
  const int wave = tid >> 6;
  const int wr = wave >> 2;
  const int wc = wave & 3;
  const int row0 = blockIdx.x * 64;

  const int sr = tid >> 3;
  const int slc = (tid & 7) ^ (sr & 7);
  const int srg = min(row0 + sr, NN - 1);
  const float* Asrc = Af + (size_t)srg * DD + slc * 8;

  int brow[4], blc[4];
#pragma unroll
  for (int q = 0; q < 4; ++q) {
    int ch = q * 512 + tid;
    brow[q] = ch >> 3;
    blc[q] = (ch & 7) ^ (brow[q] & 7);
  }

  float4v acc[2][4];
#pragma unroll
  for (int m = 0; m < 2; ++m)
#pragma unroll
    for (int n = 0; n < 4; ++n) acc[m][n] = (float4v)0.f;

  float4 pa[2][2];
  short8v pb[4];

#pragma unroll
  for (int q = 0; q < 4; ++q)
    pb[q] = *reinterpret_cast<const short8v*>(Bw + (size_t)brow[q] * DD + blc[q] * 8);
  {
    float4 f0 = *reinterpret_cast<const float4*>(Asrc);
    float4 f1 = *reinterpret_cast<const float4*>(Asrc + 4);
    short8v o;
    o[0] = (short)f2bf(f0.x); o[1] = (short)f2bf(f0.y);
    o[2] = (short)f2bf(f0.z); o[3] = (short)f2bf(f0.w);
    o[4] = (short)f2bf(f1.x); o[5] = (short)f2bf(f1.y);
    o[6] = (short)f2bf(f1.z); o[7] = (short)f2bf(f1.w);
    *reinterpret_cast<short8v*>(AsRaw + tid * 16) = o;
  }
#pragma unroll
  for (int q = 0; q < 4; ++q)
    *reinterpret_cast<short8v*>(BsRaw + (q * 512 + tid) * 16) = pb[q];
  pa[1][0] = *reinterpret_cast<const float4*>(Asrc + 64);
  pa[1][1] = *reinterpret_cast<const float4*>(Asrc + 68);
  __syncthreads();

#pragma unroll
  for (int s = 0; s < 8; ++s) {
    if (s + 1 < 8) {
#pragma unroll
      for (int q = 0; q < 4; ++q)
        pb[q] = *reinterpret_cast<const short8v*>(
            Bw + (size_t)brow[q] * DD + (s + 1) * 64 + blc[q] * 8);
    }
    if (s + 2 < 8) {
      pa[s & 1][0] = *reinterpret_cast<const float4*>(Asrc + (s + 2) * 64);
      pa[s & 1][1] = *reinterpret_cast<const float4*>(Asrc + (s + 2) * 64 + 4);
    }
    {
      const char* Bc = BsRaw + (s & 1) * 32768;
      const char* Ac = AsRaw + (s & 1) * 8192;
#pragma unroll
      for (int kk = 0; kk < 2; ++kk) {
        const int ckb = kk * 4 + (lane >> 4);
        short8v a[2], b[4];
#pragma unroll
        for (int n = 0; n < 4; ++n) {
          int rb = wc * 64 + n * 16 + (lane & 15);
          b[n] = *reinterpret_cast<const short8v*>(Bc + rb * 128 + ((ckb ^ (rb & 7)) << 4));
        }
#pragma unroll
        for (int m = 0; m < 2; ++m) {
          int ra = wr * 32 + m * 16 + (lane & 15);
          a[m] = *reinterpret_cast<const short8v*>(Ac + ra * 128 + ((ckb ^ (ra & 7)) << 4));
        }
#pragma unroll
        for (int m = 0; m < 2; ++m)
#pragma unroll
          for (int n = 0; n < 4; ++n)
            acc[m][n] = __builtin_amdgcn_mfma_f32_16x16x32_bf16(b[n], a[m], acc[m][n], 0, 0, 0);
            // swapped operands: lane row = lane&15, 4 consecutive cols
      }
    }
    if (s + 1 < 8) {
      char* Bn = BsRaw + ((s + 1) & 1) * 32768;
#pragma unroll
      for (int q = 0; q < 4; ++q)
        *reinterpret_cast<short8v*>(Bn + (q * 512 + tid) * 16) = pb[q];
      float4 f0 = pa[(s + 1) & 1][0];
      float4 f1 = pa[(s + 1) & 1][1];
      short8v o;
      o[0] = (short)f2bf(f0.x); o[1] = (short)f2bf(f0.y);
      o[2] = (short)f2bf(f0.z); o[3] = (short)f2bf(f0.w);
      o[4] = (short)f2bf(f1.x); o[5] = (short)f2bf(f1.y);
      o[6] = (short)f2bf(f1.z); o[7] = (short)f2bf(f1.w);
      *reinterpret_cast<short8v*>(AsRaw + ((s + 1) & 1) * 8192 + tid * 16) = o;
    }
    __syncthreads();
  }

  const int crow = lane & 15;
  const int cg = (lane >> 4) * 4;
#pragma unroll
  for (int m = 0; m < 2; ++m) {
    int rg = row0 + wr * 32 + m * 16 + crow;
    if (rg >= NN) continue;
#pragma unroll
    for (int n = 0; n < 4; ++n) {
      int colb = wc * 64 + n * 16 + cg;
      size_t off = (size_t)rg * HH + colb;
      float4v bi = *reinterpret_cast<const float4v*>(bias + colb);
      short4v o;
#pragma unroll
      for (int i = 0; i < 4; ++i) o[i] = (short)f2bf(acc[m][n][i] + bi[i]);
      *reinterpret_cast<short4v*>(Cb + off) = o;
    }
  }
}

// Fused epoch, BM=256 x BN=256, BK=64, 1024 threads = 16 waves (4M x 4N,
// per-wave 64x64 -> per-wave code identical to the proven BM=128 version).
// B tile (32KB/step) now amortized over 256 output rows (2x arithmetic
// intensity per staged B byte); LDS = B 32K + A 32K + nbr 5K = 69 KB ->
// 2 blocks/CU IF VGPR stays at the measured 64 (cap 128 via (1024,4), same
// cap as the proven (512,4) -> no r8/r9-style cap<need cliff).
// h' = Bcat . [D ; mean_j D[nbr] ; Cc] + bc   (K = 768, 12 steps of BK=64)
// EPI 0: store bf16. EPI 2: relu -> bf16. EPI 3: relu, avg with Fin -> fp32.
template<int EPI>
__global__ __launch_bounds__(1024, 4) void epoch_k(
    const short* __restrict__ D0_, const short* __restrict__ C0_,
    short* __restrict__ O0_, const int* __restrict__ n0_,
    const short* __restrict__ D1_, const short* __restrict__ C1_,
    short* __restrict__ O1_, const int* __restrict__ n1_,
    const short* __restrict__ Bw, const float* __restrict__ bias,
    float* __restrict__ Of, const short* __restrict__ Fin)
{
  __shared__ __align__(16) char BsRaw[256 * 64 * 2];   // 32 KB
  __shared__ __align__(16) char AsRaw[256 * 64 * 2];   // 32 KB
  __shared__ int nbrL[256][KNB];                       // 5 KB

  const short* D  = blockIdx.y ? D1_ : D0_;
  const short* Cc = blockIdx.y ? C1_ : C0_;
  short* Ob       = blockIdx.y ? O1_ : O0_;
  const int* nbr  = blockIdx.y ? n1_ : n0_;

  const int tid = threadIdx.x;
  const int lane = tid & 63;
  const int wave = tid >> 6;     // 0..15
  const int wr = wave >> 2;      // 0..3 (M quarter)
  const int wc = wave & 3;       // 0..3 (N quadrant)
  const int row0 = blockIdx.x * 256;

  // preload neighbor indices (first gather use is step 4; barriers intervene)
  for (int e = tid; e < 256 * KNB; e += 1024) {
    int r = e / KNB;
    int rg = min(row0 + r, NN - 1);
    nbrL[r][e - r * KNB] = nbr[rg * KNB + (e - r * KNB)];
  }

  float4v acc[4][4];
#pragma unroll
  for (int m = 0; m < 4; ++m)
#pragma unroll
    for (int n = 0; n < 4; ++n) acc[m][n] = (float4v)0.f;

  for (int k0 = 0; k0 < 768; k0 += 64) {
    // B tile [256][64]: 2048 chunks, 2/thread
#pragma unroll
    for (int q = 0; q < 2; ++q) {
      int ch = q * 1024 + tid;
      int r = ch >> 3, pc = ch & 7;
      int lc = pc ^ (r & 7);
      GLOAD16(Bw + (size_t)r * 768 + k0 + lc * 8, BsRaw + (q * 1024 + wave * 64) * 16);
    }
    // A tile [256][64] bf16: 2048 chunks, 2/thread
    if (k0 < 256 || k0 >= 512) {
      const short* H = (k0 < 256) ? (D + k0) : (Cc + (k0 - 512));
#pragma unroll
      for (int q = 0; q < 2; ++q) {
        int ch = q * 1024 + tid;
        int r = ch >> 3, pc = ch & 7;
        int lc = pc ^ (r & 7);
        int rg = min(row0 + r, NN - 1);
        GLOAD16(H + (size_t)rg * HH + lc * 8, AsRaw + (q * 1024 + wave * 64) * 16);
      }
    } else {
      const int kb = k0 - 256;
#pragma unroll
      for (int q = 0; q < 2; ++q) {
        int ch = q * 1024 + tid;
        int r = ch >> 3, pc = ch & 7;
        int lc = pc ^ (r & 7);
        float a8[8] = {0.f, 0.f, 0.f, 0.f, 0.f, 0.f, 0.f, 0.f};
#pragma unroll
        for (int j = 0; j < KNB; ++j) {
          int id = nbrL[r][j];
          short8v v = *reinterpret_cast<const short8v*>(D + (size_t)id * HH + kb + lc * 8);
#pragma unroll
          for (int x = 0; x < 8; ++x) a8[x] += bf2f((unsigned short)v[x]);
        }
        short8v o;
#pragma unroll
        for (int x = 0; x < 8; ++x) o[x] = (short)f2bf(a8[x] * 0.2f);
        *reinterpret_cast<short8v*>(AsRaw + ch * 16) = o;
      }
    }
    __syncthreads();

#pragma unroll
    for (int kk = 0; kk < 2; ++kk) {
      const int ckb = kk * 4 + (lane >> 4);
      short8v a[4], b[4];
#pragma unroll
      for (int n = 0; n < 4; ++n) {
        int rb = wc * 64 + n * 16 + (lane & 15);
        b[n] = *reinterpret_cast<const short8v*>(BsRaw + rb * 128 + ((ckb ^ (rb & 7)) << 4));
      }
#pragma unroll
      for (int m = 0; m < 4; ++m) {
        int ra = wr * 64 + m * 16 + (lane & 15);
        a[m] = *reinterpret_cast<const short8v*>(AsRaw + ra * 128 + ((ckb ^ (ra & 7)) << 4));
      }
#pragma unroll
      for (int m = 0; m < 4; ++m)
#pragma unroll
        for (int n = 0; n < 4; ++n)
          acc[m][n] = __builtin_amdgcn_mfma_f32_16x16x32_bf16(b[n], a[m], acc[m][n], 0, 0, 0);
          // swapped operands: lane row = lane&15, 4 consecutive cols
    }
    __syncthreads();
  }

  // epilogue: lane owns row (lane&15), 4 consecutive cols -> vectorized
  const int crow = lane & 15;
  const int cg = (lane >> 4) * 4;
#pragma unroll
  for (int m = 0; m < 4; ++m) {
    int rg = row0 + wr * 64 + m * 16 + crow;
    if (rg >= NN) continue;
#pragma unroll
    for (int n = 0; n < 4; ++n) {
      int colb = wc * 64 + n * 16 + cg;
      size_t off = (size_t)rg * HH + colb;
      float4v bi = *reinterpret_cast<const float4v*>(bias + colb);
      float v[4];
#pragma unroll
      for (int i = 0; i < 4; ++i) v[i] = acc[m][n][i] + bi[i];
      if constexpr (EPI >= 2) {
#pragma unroll
        for (int i = 0; i < 4; ++i) v[i] = fmaxf(v[i], 0.f);
      }
      if constexpr (EPI <= 2) {
        short4v o;
#pragma unroll
        for (int i = 0; i < 4; ++i) o[i] = (short)f2bf(v[i]);
        *reinterpret_cast<short4v*>(Ob + off) = o;
      } else {
        short4v f4 = *reinterpret_cast<const short4v*>(Fin + off);
        float4v o;
#pragma unroll
        for (int i = 0; i < 4; ++i)
          o[i] = (v[i] + bf2f((unsigned short)f4[i])) * 0.5f;
        *reinterpret_cast<float4v*>(Of + off) = o;
      }
    }
  }
}

extern "C" void kernel_launch(void* const* d_in, const int* in_sizes, int n_in,
                              void* d_out, int out_size, void* d_ws, size_t ws_size,
                              hipStream_t stream) {
  const float* x0  = (const float*)d_in[0];
  const float* x1  = (const float*)d_in[1];
  const float* wh0 = (const float*)d_in[2];
  const float* bh0 = (const float*)d_in[3];
  const float* wh1 = (const float*)d_in[4];
  const float* bh1 = (const float*)d_in[5];
  const float* w0  = (const float*)d_in[6];
  const float* b0  = (const float*)d_in[7];
  const float* w1  = (const float*)d_in[8];
  const float* b1  = (const float*)d_in[9];
  const float* w2  = (const float*)d_in[10];
  const float* b2  = (const float*)d_in[11];
  const int* e0    = (const int*)d_in[12];
  const int* e1    = (const int*)d_in[13];
  const int* nbr0  = e0 + (size_t)NN * KNB;  // edge[1]
  const int* nbr1  = e1 + (size_t)NN * KNB;
  float* out       = (float*)d_out;

  char* ws = (char*)d_ws;
  size_t off = 0;
  auto alloc = [&](size_t bytes) -> void* {
    off = (off + 255) & ~(size_t)255;
    void* p = ws + off;
    off += bytes;
    return p;
  };

  short* Wh0  = (short*)alloc((size_t)HH * DD * 2);
  short* Wh1  = (short*)alloc((size_t)HH * DD * 2);
  short* Bcat = (short*)alloc((size_t)HH * 768 * 2);
  float* bc   = (float*)alloc((size_t)HH * 4);
  const size_t NB = (size_t)NN * HH * 2;
  short* hi0 = (short*)alloc(NB);
  short* hi1 = (short*)alloc(NB);
  short* hb0 = (short*)alloc(NB);
  short* hb1 = (short*)alloc(NB);
  short* f0  = (short*)alloc(NB);

  // weight prep
  cvt2<<<dim3(256), dim3(256), 0, stream>>>(wh0, Wh0, wh1, Wh1);
  prep_w01<<<dim3(256), dim3(256), 0, stream>>>(w0, w1, w2, b0, b1, b2, Bcat, bc);

  // both projections (round-12 form, 165 us)
  proj_k<<<dim3((NN + 63) / 64, 2), dim3(512), 0, stream>>>(
      x0, x1, Wh0, Wh1, bh0, bh1, hi0, hi1);

  dim3 ge((NN + 255) / 256);       // 391 blocks per view

  // epoch 1: both views in one launch (independent; L3 set ~205 MB < 256 MB)
  epoch_k<0><<<dim3(ge.x, 2), dim3(1024), 0, stream>>>(
      hi0, hi1, hb0, nbr0,  hi1, hi0, hb1, nbr1,  Bcat, bc, nullptr, nullptr);

  // epoch 2 view0: f0 = relu(...) bf16
  epoch_k<2><<<dim3(ge.x, 1), dim3(1024), 0, stream>>>(
      hb0, hi1, f0, nbr0,   hb0, hi1, f0, nbr0,   Bcat, bc, nullptr, nullptr);

  // epoch 2 view1: out = 0.5*(relu(...) + f0) fp32
  epoch_k<3><<<dim3(ge.x, 1), dim3(1024), 0, stream>>>(
      hb1, hi0, nullptr, nbr1,  hb1, hi0, nullptr, nbr1,  Bcat, bc, out, f0);

  (void)in_sizes; (void)n_in; (void)out_size; (void)ws_size;
}

// Round 18
// 521.118 us; speedup vs baseline: 1.0638x; 1.0638x over previous
//
#include <hip/hip_runtime.h>

#define NN 100000
#define DD 512
#define HH 256
#define KNB 5

typedef __attribute__((ext_vector_type(8))) short short8v;
typedef __attribute__((ext_vector_type(4))) short short4v;
typedef __attribute__((ext_vector_type(4))) float float4v;

static __device__ __forceinline__ float bf2f(unsigned short u) {
  union { unsigned int i; float f; } c;
  c.i = ((unsigned int)u) << 16;
  return c.f;
}
static __device__ __forceinline__ unsigned short f2bf(float f) {
  union { float f; unsigned int i; } c;
  c.f = f;
  unsigned int u = c.i;
  u += 0x7FFFu + ((u >> 16) & 1u);   // round-to-nearest-even
  return (unsigned short)(u >> 16);
}

// async global->LDS, 16B per lane; lds dest base must be wave-uniform
#define GLOAD16(g, l) __builtin_amdgcn_global_load_lds( \
    (const __attribute__((address_space(1))) unsigned int*)(g), \
    (__attribute__((address_space(3))) unsigned int*)(l), 16, 0, 0)

// bf16 conversion of the two input-projection weights
__global__ void cvt2(const float* __restrict__ s0, short* __restrict__ d0,
                     const float* __restrict__ s1, short* __restrict__ d1) {
  const int S1 = (HH * DD) / 4;
  int i = blockIdx.x * blockDim.x + threadIdx.x;
  if (i >= 2 * S1) return;
  const float* s = (i < S1) ? s0 : s1;
  short* d = (i < S1) ? d0 : d1;
  int j = (i < S1) ? i : i - S1;
  float4 v = reinterpret_cast<const float4*>(s)[j];
  short4v o;
  o[0] = (short)f2bf(v.x); o[1] = (short)f2bf(v.y);
  o[2] = (short)f2bf(v.z); o[3] = (short)f2bf(v.w);
  reinterpret_cast<short4v*>(d)[j] = o;
}

// Bcat [256][768] = [w0 | W01=w1@w0 | w2] bf16; bc[i] = b0+b1+b2 + w1@b0 (fp32)
__global__ void prep_w01(const float* __restrict__ w0, const float* __restrict__ w1,
                         const float* __restrict__ w2, const float* __restrict__ b0,
                         const float* __restrict__ b1, const float* __restrict__ b2,
                         short* __restrict__ Bcat, float* __restrict__ bc) {
  int i = blockIdx.x;      // output row 0..255
  int j = threadIdx.x;     // col 0..255
  Bcat[(size_t)i * 768 + j]       = (short)f2bf(w0[i * 256 + j]);
  Bcat[(size_t)i * 768 + 512 + j] = (short)f2bf(w2[i * 256 + j]);
  float acc = 0.f;
  for (int k = 0; k < 256; ++k)
    acc = fmaf(w1[i * 256 + k], w0[k * 256 + j], acc);
  Bcat[(size_t)i * 768 + 256 + j] = (short)f2bf(acc);
  if (j == 0) {
    float s = b0[i] + b1[i] + b2[i];
    for (int k = 0; k < 256; ++k) s = fmaf(w1[i * 256 + k], b0[k], s);
    bc[i] = s;
  }
}

// Projection (round-12 proven, 165 us best-of-6-schedules): all-reg-staged
// dbuf pipeline. BM=64, BN=256, BK=64, 8 waves (2M x 4N -> wave tile 32x64).
// LDS: B dbuf 64K + A dbuf 16K = 80 KB. (512,2): VGPR 64, no spill. FROZEN.
__global__ __launch_bounds__(512, 2) void proj_k(
    const float* __restrict__ Af0, const float* __restrict__ Af1,
    const short* __restrict__ Bw0, const short* __restrict__ Bw1,
    const float* __restrict__ bi0, const float* __restrict__ bi1,
    short* __restrict__ Cb0, short* __restrict__ Cb1)
{
  const float* Af = blockIdx.y ? Af1 : Af0;
  const short* Bw = blockIdx.y ? Bw1 : Bw0;
  const float* bias = blockIdx.y ? bi1 : bi0;
  short* Cb = blockIdx.y ? Cb1 : Cb0;

  __shared__ __align__(16) char BsRaw[2 * 256 * 64 * 2];  // 64 KB dbuf, XOR-swizzled
  __shared__ __align__(16) char AsRaw[2 * 64 * 64 * 2];   // 16 KB dbuf bf16

  const int tid = threadIdx.x;
  const int lane = tid & 63;
  const int wave = tid >> 6;
  const int wr = wave >> 2;
  const int wc = wave & 3;
  const int row0 = blockIdx.x * 64;

  const int sr = tid >> 3;
  const int slc = (tid & 7) ^ (sr & 7);
  const int srg = min(row0 + sr, NN - 1);
  const float* Asrc = Af + (size_t)srg * DD + slc * 8;

  int brow[4], blc[4];
#pragma unroll
  for (int q = 0; q < 4; ++q) {
    int ch = q * 512 + tid;
    brow[q] = ch >> 3;
    blc[q] = (ch & 7) ^ (brow[q] & 7);
  }

  float4v acc[2][4];
#pragma unroll
  for (int m = 0; m < 2; ++m)
#pragma unroll
    for (int n = 0; n < 4; ++n) acc[m][n] = (float4v)0.f;

  float4 pa[2][2];
  short8v pb[4];

#pragma unroll
  for (int q = 0; q < 4; ++q)
    pb[q] = *reinterpret_cast<const short8v*>(Bw + (size_t)brow[q] * DD + blc[q] * 8);
  {
    float4 f0 = *reinterpret_cast<const float4*>(Asrc);
    float4 f1 = *reinterpret_cast<const float4*>(Asrc + 4);
    short8v o;
    o[0] = (short)f2bf(f0.x); o[1] = (short)f2bf(f0.y);
    o[2] = (short)f2bf(f0.z); o[3] = (short)f2bf(f0.w);
    o[4] = (short)f2bf(f1.x); o[5] = (short)f2bf(f1.y);
    o[6] = (short)f2bf(f1.z); o[7] = (short)f2bf(f1.w);
    *reinterpret_cast<short8v*>(AsRaw + tid * 16) = o;
  }
#pragma unroll
  for (int q = 0; q < 4; ++q)
    *reinterpret_cast<short8v*>(BsRaw + (q * 512 + tid) * 16) = pb[q];
  pa[1][0] = *reinterpret_cast<const float4*>(Asrc + 64);
  pa[1][1] = *reinterpret_cast<const float4*>(Asrc + 68);
  __syncthreads();

#pragma unroll
  for (int s = 0; s < 8; ++s) {
    if (s + 1 < 8) {
#pragma unroll
      for (int q = 0; q < 4; ++q)
        pb[q] = *reinterpret_cast<const short8v*>(
            Bw + (size_t)brow[q] * DD + (s + 1) * 64 + blc[q] * 8);
    }
    if (s + 2 < 8) {
      pa[s & 1][0] = *reinterpret_cast<const float4*>(Asrc + (s + 2) * 64);
      pa[s & 1][1] = *reinterpret_cast<const float4*>(Asrc + (s + 2) * 64 + 4);
    }
    {
      const char* Bc = BsRaw + (s & 1) * 32768;
      const char* Ac = AsRaw + (s & 1) * 8192;
#pragma unroll
      for (int kk = 0; kk < 2; ++kk) {
        const int ckb = kk * 4 + (lane >> 4);
        short8v a[2], b[4];
#pragma unroll
        for (int n = 0; n < 4; ++n) {
          int rb = wc * 64 + n * 16 + (lane & 15);
          b[n] = *reinterpret_cast<const short8v*>(Bc + rb * 128 + ((ckb ^ (rb & 7)) << 4));
        }
#pragma unroll
        for (int m = 0; m < 2; ++m) {
          int ra = wr * 32 + m * 16 + (lane & 15);
          a[m] = *reinterpret_cast<const short8v*>(Ac + ra * 128 + ((ckb ^ (ra & 7)) << 4));
        }
#pragma unroll
        for (int m = 0; m < 2; ++m)
#pragma unroll
          for (int n = 0; n < 4; ++n)
            acc[m][n] = __builtin_amdgcn_mfma_f32_16x16x32_bf16(b[n], a[m], acc[m][n], 0, 0, 0);
            // swapped operands: lane row = lane&15, 4 consecutive cols
      }
    }
    if (s + 1 < 8) {
      char* Bn = BsRaw + ((s + 1) & 1) * 32768;
#pragma unroll
      for (int q = 0; q < 4; ++q)
        *reinterpret_cast<short8v*>(Bn + (q * 512 + tid) * 16) = pb[q];
      float4 f0 = pa[(s + 1) & 1][0];
      float4 f1 = pa[(s + 1) & 1][1];
      short8v o;
      o[0] = (short)f2bf(f0.x); o[1] = (short)f2bf(f0.y);
      o[2] = (short)f2bf(f0.z); o[3] = (short)f2bf(f0.w);
      o[4] = (short)f2bf(f1.x); o[5] = (short)f2bf(f1.y);
      o[6] = (short)f2bf(f1.z); o[7] = (short)f2bf(f1.w);
      *reinterpret_cast<short8v*>(AsRaw + ((s + 1) & 1) * 8192 + tid * 16) = o;
    }
    __syncthreads();
  }

  const int crow = lane & 15;
  const int cg = (lane >> 4) * 4;
#pragma unroll
  for (int m = 0; m < 2; ++m) {
    int rg = row0 + wr * 32 + m * 16 + crow;
    if (rg >= NN) continue;
#pragma unroll
    for (int n = 0; n < 4; ++n) {
      int colb = wc * 64 + n * 16 + cg;
      size_t off = (size_t)rg * HH + colb;
      float4v bi = *reinterpret_cast<const float4v*>(bias + colb);
      short4v o;
#pragma unroll
      for (int i = 0; i < 4; ++i) o[i] = (short)f2bf(acc[m][n][i] + bi[i]);
      *reinterpret_cast<short4v*>(Cb + off) = o;
    }
  }
}

// Fused epoch (round-13/16 proven, best epoch form measured): BM=128, BN=256,
// BK=64, serial staged, (512,4) -> 3 blocks/CU. Dual-view via blockIdx.y.
// BM=256/16-wave variant regressed (r17: deeper barrier drain, occ 35%).
// h' = Bcat . [D ; mean_j D[nbr] ; Cc] + bc   (K = 768, 12 steps of BK=64)
// EPI 0: store bf16. EPI 2: relu -> bf16. EPI 3: relu, avg with Fin -> fp32.
template<int EPI>
__global__ __launch_bounds__(512, 4) void epoch_k(
    const short* __restrict__ D0_, const short* __restrict__ C0_,
    short* __restrict__ O0_, const int* __restrict__ n0_,
    const short* __restrict__ D1_, const short* __restrict__ C1_,
    short* __restrict__ O1_, const int* __restrict__ n1_,
    const short* __restrict__ Bw, const float* __restrict__ bias,
    float* __restrict__ Of, const short* __restrict__ Fin)
{
  __shared__ __align__(16) char BsRaw[256 * 64 * 2];   // 32 KB
  __shared__ __align__(16) char AsRaw[128 * 64 * 2];   // 16 KB
  __shared__ int nbrL[128][KNB];                       // 2.5 KB

  const short* D  = blockIdx.y ? D1_ : D0_;
  const short* Cc = blockIdx.y ? C1_ : C0_;
  short* Ob       = blockIdx.y ? O1_ : O0_;
  const int* nbr  = blockIdx.y ? n1_ : n0_;

  const int tid = threadIdx.x;
  const int lane = tid & 63;
  const int wave = tid >> 6;
  const int wr = wave >> 2;      // 0..1 (M)
  const int wc = wave & 3;       // 0..3 (N)
  const int row0 = blockIdx.x * 128;

  // preload neighbor indices (first gather use is step 4; barriers intervene)
  for (int e = tid; e < 128 * KNB; e += 512) {
    int r = e / KNB;
    int rg = min(row0 + r, NN - 1);
    nbrL[r][e - r * KNB] = nbr[rg * KNB + (e - r * KNB)];
  }

  float4v acc[4][4];
#pragma unroll
  for (int m = 0; m < 4; ++m)
#pragma unroll
    for (int n = 0; n < 4; ++n) acc[m][n] = (float4v)0.f;

  for (int k0 = 0; k0 < 768; k0 += 64) {
    // B tile [256][64]: 2048 chunks, 4/thread
#pragma unroll
    for (int q = 0; q < 4; ++q) {
      int ch = q * 512 + tid;
      int r = ch >> 3, pc = ch & 7;
      int lc = pc ^ (r & 7);
      GLOAD16(Bw + (size_t)r * 768 + k0 + lc * 8, BsRaw + (q * 512 + wave * 64) * 16);
    }
    // A tile [128][64] bf16: 1024 chunks, 2/thread
    if (k0 < 256 || k0 >= 512) {
      const short* H = (k0 < 256) ? (D + k0) : (Cc + (k0 - 512));
#pragma unroll
      for (int q = 0; q < 2; ++q) {
        int ch = q * 512 + tid;
        int r = ch >> 3, pc = ch & 7;
        int lc = pc ^ (r & 7);
        int rg = min(row0 + r, NN - 1);
        GLOAD16(H + (size_t)rg * HH + lc * 8, AsRaw + (q * 512 + wave * 64) * 16);
      }
    } else {
      const int kb = k0 - 256;
#pragma unroll
      for (int q = 0; q < 2; ++q) {
        int ch = q * 512 + tid;
        int r = ch >> 3, pc = ch & 7;
        int lc = pc ^ (r & 7);
        float a8[8] = {0.f, 0.f, 0.f, 0.f, 0.f, 0.f, 0.f, 0.f};
#pragma unroll
        for (int j = 0; j < KNB; ++j) {
          int id = nbrL[r][j];
          short8v v = *reinterpret_cast<const short8v*>(D + (size_t)id * HH + kb + lc * 8);
#pragma unroll
          for (int x = 0; x < 8; ++x) a8[x] += bf2f((unsigned short)v[x]);
        }
        short8v o;
#pragma unroll
        for (int x = 0; x < 8; ++x) o[x] = (short)f2bf(a8[x] * 0.2f);
        *reinterpret_cast<short8v*>(AsRaw + ch * 16) = o;
      }
    }
    __syncthreads();

#pragma unroll
    for (int kk = 0; kk < 2; ++kk) {
      const int ckb = kk * 4 + (lane >> 4);
      short8v a[4], b[4];
#pragma unroll
      for (int n = 0; n < 4; ++n) {
        int rb = wc * 64 + n * 16 + (lane & 15);
        b[n] = *reinterpret_cast<const short8v*>(BsRaw + rb * 128 + ((ckb ^ (rb & 7)) << 4));
      }
#pragma unroll
      for (int m = 0; m < 4; ++m) {
        int ra = wr * 64 + m * 16 + (lane & 15);
        a[m] = *reinterpret_cast<const short8v*>(AsRaw + ra * 128 + ((ckb ^ (ra & 7)) << 4));
      }
#pragma unroll
      for (int m = 0; m < 4; ++m)
#pragma unroll
        for (int n = 0; n < 4; ++n)
          acc[m][n] = __builtin_amdgcn_mfma_f32_16x16x32_bf16(b[n], a[m], acc[m][n], 0, 0, 0);
          // swapped operands: lane row = lane&15, 4 consecutive cols
    }
    __syncthreads();
  }

  // epilogue: lane owns row (lane&15), 4 consecutive cols -> vectorized
  const int crow = lane & 15;
  const int cg = (lane >> 4) * 4;
#pragma unroll
  for (int m = 0; m < 4; ++m) {
    int rg = row0 + wr * 64 + m * 16 + crow;
    if (rg >= NN) continue;
#pragma unroll
    for (int n = 0; n < 4; ++n) {
      int colb = wc * 64 + n * 16 + cg;
      size_t off = (size_t)rg * HH + colb;
      float4v bi = *reinterpret_cast<const float4v*>(bias + colb);
      float v[4];
#pragma unroll
      for (int i = 0; i < 4; ++i) v[i] = acc[m][n][i] + bi[i];
      if constexpr (EPI >= 2) {
#pragma unroll
        for (int i = 0; i < 4; ++i) v[i] = fmaxf(v[i], 0.f);
      }
      if constexpr (EPI <= 2) {
        short4v o;
#pragma unroll
        for (int i = 0; i < 4; ++i) o[i] = (short)f2bf(v[i]);
        *reinterpret_cast<short4v*>(Ob + off) = o;
      } else {
        short4v f4 = *reinterpret_cast<const short4v*>(Fin + off);
        float4v o;
#pragma unroll
        for (int i = 0; i < 4; ++i)
          o[i] = (v[i] + bf2f((unsigned short)f4[i])) * 0.5f;
        *reinterpret_cast<float4v*>(Of + off) = o;
      }
    }
  }
}

extern "C" void kernel_launch(void* const* d_in, const int* in_sizes, int n_in,
                              void* d_out, int out_size, void* d_ws, size_t ws_size,
                              hipStream_t stream) {
  const float* x0  = (const float*)d_in[0];
  const float* x1  = (const float*)d_in[1];
  const float* wh0 = (const float*)d_in[2];
  const float* bh0 = (const float*)d_in[3];
  const float* wh1 = (const float*)d_in[4];
  const float* bh1 = (const float*)d_in[5];
  const float* w0  = (const float*)d_in[6];
  const float* b0  = (const float*)d_in[7];
  const float* w1  = (const float*)d_in[8];
  const float* b1  = (const float*)d_in[9];
  const float* w2  = (const float*)d_in[10];
  const float* b2  = (const float*)d_in[11];
  const int* e0    = (const int*)d_in[12];
  const int* e1    = (const int*)d_in[13];
  const int* nbr0  = e0 + (size_t)NN * KNB;  // edge[1]
  const int* nbr1  = e1 + (size_t)NN * KNB;
  float* out       = (float*)d_out;

  char* ws = (char*)d_ws;
  size_t off = 0;
  auto alloc = [&](size_t bytes) -> void* {
    off = (off + 255) & ~(size_t)255;
    void* p = ws + off;
    off += bytes;
    return p;
  };

  short* Wh0  = (short*)alloc((size_t)HH * DD * 2);
  short* Wh1  = (short*)alloc((size_t)HH * DD * 2);
  short* Bcat = (short*)alloc((size_t)HH * 768 * 2);
  float* bc   = (float*)alloc((size_t)HH * 4);
  const size_t NB = (size_t)NN * HH * 2;
  short* hi0 = (short*)alloc(NB);
  short* hi1 = (short*)alloc(NB);
  short* hb0 = (short*)alloc(NB);
  short* hb1 = (short*)alloc(NB);
  short* f0  = (short*)alloc(NB);

  // weight prep
  cvt2<<<dim3(256), dim3(256), 0, stream>>>(wh0, Wh0, wh1, Wh1);
  prep_w01<<<dim3(256), dim3(256), 0, stream>>>(w0, w1, w2, b0, b1, b2, Bcat, bc);

  // both projections (round-12 form, 165 us)
  proj_k<<<dim3((NN + 63) / 64, 2), dim3(512), 0, stream>>>(
      x0, x1, Wh0, Wh1, bh0, bh1, hi0, hi1);

  dim3 ge((NN + 127) / 128);       // 782 blocks per view

  // epoch 1: both views in one launch (independent; L3 set ~205 MB < 256 MB)
  epoch_k<0><<<dim3(ge.x, 2), dim3(512), 0, stream>>>(
      hi0, hi1, hb0, nbr0,  hi1, hi0, hb1, nbr1,  Bcat, bc, nullptr, nullptr);

  // epoch 2 view0: f0 = relu(...) bf16
  epoch_k<2><<<dim3(ge.x, 1), dim3(512), 0, stream>>>(
      hb0, hi1, f0, nbr0,   hb0, hi1, f0, nbr0,   Bcat, bc, nullptr, nullptr);

  // epoch 2 view1: out = 0.5*(relu(...) + f0) fp32
  epoch_k<3><<<dim3(ge.x, 1), dim3(512), 0, stream>>>(
      hb1, hi0, nullptr, nbr1,  hb1, hi0, nullptr, nbr1,  Bcat, bc, out, f0);

  (void)in_sizes; (void)n_in; (void)out_size; (void)ws_size;
}